// Round 2
// 1669.402 us; speedup vs baseline: 1.7097x; 1.7097x over previous
//
#include <hip/hip_runtime.h>
#include <math.h>

#define D 512
#define P 8
#define NL 4
#define BB 2
#define LL 2048
#define VV 32000
#define MTOK (BB*LL)   // 4096
#define CH 128
#define NCH (LL/CH)    // 16

__device__ __forceinline__ float softplusf(float x){
    if (x > 20.f) return x;
    return log1pf(expf(x));
}

// ---------------- bf16 split helpers ----------------
__device__ __forceinline__ unsigned short f2bf(float f){
    unsigned int u = __float_as_uint(f);
    unsigned int r = (u + 0x7fffu + ((u >> 16) & 1u)) >> 16;
    return (unsigned short)r;
}
__device__ __forceinline__ float bf2f(unsigned short h){
    return __uint_as_float((unsigned int)h << 16);
}

typedef __attribute__((ext_vector_type(8))) short short8;
typedef __attribute__((ext_vector_type(4))) float f32x4;

__device__ __forceinline__ void gload16(const void* g, void* l){
    // async global->LDS, 16B/lane; LDS dest = wave-uniform base + lane*16
    __builtin_amdgcn_global_load_lds(
        (const __attribute__((address_space(1))) void*)g,
        (__attribute__((address_space(3))) void*)l, 16, 0, 0);
}

// ---------------- embedding gather: h[t,:] = embed[tokens[t],:] ----------------
__global__ void gather_kernel(const int* __restrict__ tokens,
                              const float* __restrict__ embed,
                              float* __restrict__ h){
    int t = blockIdx.x;
    int tok = tokens[t];
    const float4* src = (const float4*)(embed + (size_t)tok * D);
    float4* dst = (float4*)(h + (size_t)t * D);
    dst[threadIdx.x] = src[threadIdx.x];
}

// ---------------- per-token LayerNorm (block = 128 threads, D=512) -------------
__global__ void ln_kernel(const float* __restrict__ x,
                          const float* __restrict__ g,
                          const float* __restrict__ b,
                          float* __restrict__ y){
    int t = blockIdx.x;
    int tid = threadIdx.x;
    const float4* xr = (const float4*)(x + (size_t)t * D);
    float4 v = xr[tid];
    float s = v.x + v.y + v.z + v.w;
    float q = v.x*v.x + v.y*v.y + v.z*v.z + v.w*v.w;
    #pragma unroll
    for (int off = 32; off; off >>= 1){
        s += __shfl_down(s, off);
        q += __shfl_down(q, off);
    }
    __shared__ float red[4];
    int wid = tid >> 6, lane = tid & 63;
    if (lane == 0){ red[wid] = s; red[2 + wid] = q; }
    __syncthreads();
    float mean = (red[0] + red[1]) * (1.f / D);
    float var  = (red[2] + red[3]) * (1.f / D) - mean * mean;
    float rstd = rsqrtf(var + 1e-5f);
    float4 gg = ((const float4*)g)[tid];
    float4 bb = ((const float4*)b)[tid];
    float4 o;
    o.x = (v.x - mean) * rstd * gg.x + bb.x;
    o.y = (v.y - mean) * rstd * gg.y + bb.y;
    o.z = (v.z - mean) * rstd * gg.z + bb.z;
    o.w = (v.w - mean) * rstd * gg.w + bb.w;
    ((float4*)(y + (size_t)t * D))[tid] = o;
}

// --------- phase/amp projections + per-token coefficient c (1 wave/token) ------
__global__ void proj_kernel(const float* __restrict__ hn,
                            const float* __restrict__ pW, const float* __restrict__ pb,
                            const float* __restrict__ aW, const float* __restrict__ ab,
                            float* __restrict__ cbuf){
    int wid = threadIdx.x >> 6;
    int lane = threadIdx.x & 63;
    int t = blockIdx.x * 4 + wid;
    const float* x = hn + (size_t)t * D;
    float ph[P] = {0.f,0.f,0.f,0.f,0.f,0.f,0.f,0.f};
    float am[P] = {0.f,0.f,0.f,0.f,0.f,0.f,0.f,0.f};
    int d0 = lane * 8;
    #pragma unroll
    for (int j = 0; j < 8; j++){
        float xv = x[d0 + j];
        const float* pr = pW + (size_t)(d0 + j) * P;
        const float* ar = aW + (size_t)(d0 + j) * P;
        #pragma unroll
        for (int p = 0; p < P; p++){ ph[p] += xv * pr[p]; am[p] += xv * ar[p]; }
    }
    #pragma unroll
    for (int off = 32; off; off >>= 1){
        #pragma unroll
        for (int p = 0; p < P; p++){
            ph[p] += __shfl_down(ph[p], off);
            am[p] += __shfl_down(am[p], off);
        }
    }
    if (lane == 0){
        float c = 0.f;
        #pragma unroll
        for (int p = 0; p < P; p++){
            float phase = tanhf(ph[p] + pb[p]) * 3.14159265358979323846f;
            float amp = softplusf(am[p] + ab[p]) + 0.1f;
            c += amp * (cosf(phase) + sinf(phase));
        }
        cbuf[t] = c;
    }
}

// ---------------- generic fp32 tiled GEMM: C = epi(A@B + bias) -----------------
// A: MxK row-major, B: KxN row-major. epilogue: v=(acc+bias[n]); v*=rowscale[m];
// v+=R1; v+=R2; C=v.   BM=BN=64, BK=16, 256 thr, 4x4 micro-tile.
__global__ __launch_bounds__(256) void gemm_kernel(
    const float* __restrict__ A, const float* __restrict__ B,
    const float* __restrict__ bias, const float* __restrict__ rowscale,
    const float* __restrict__ R1, const float* __restrict__ R2,
    float* __restrict__ C, int M, int N, int K)
{
    __shared__ float As[16][64];
    __shared__ float Bs[16][64];
    int bn = blockIdx.x * 64, bm = blockIdx.y * 64;
    int tid = threadIdx.x;
    int tx = tid & 15, ty = tid >> 4;
    float acc[4][4] = {};
    int arow = tid >> 2, acol = (tid & 3) * 4;
    int brow = tid >> 4, bcol = (tid & 15) * 4;
    for (int k0 = 0; k0 < K; k0 += 16){
        float4 av = *(const float4*)(A + (size_t)(bm + arow) * K + k0 + acol);
        As[acol + 0][arow] = av.x; As[acol + 1][arow] = av.y;
        As[acol + 2][arow] = av.z; As[acol + 3][arow] = av.w;
        float4 bv = *(const float4*)(B + (size_t)(k0 + brow) * N + bn + bcol);
        *(float4*)(&Bs[brow][bcol]) = bv;
        __syncthreads();
        #pragma unroll
        for (int k = 0; k < 16; k++){
            float ar[4], br[4];
            #pragma unroll
            for (int i = 0; i < 4; i++) ar[i] = As[k][ty * 4 + i];
            #pragma unroll
            for (int j = 0; j < 4; j++) br[j] = Bs[k][tx * 4 + j];
            #pragma unroll
            for (int i = 0; i < 4; i++)
                #pragma unroll
                for (int j = 0; j < 4; j++)
                    acc[i][j] += ar[i] * br[j];
        }
        __syncthreads();
    }
    float4 bi = *(const float4*)(bias + bn + tx * 4);
    #pragma unroll
    for (int i = 0; i < 4; i++){
        int m = bm + ty * 4 + i;
        float rs = rowscale ? rowscale[m] : 1.f;
        size_t idx = (size_t)m * N + bn + tx * 4;
        float4 v;
        v.x = (acc[i][0] + bi.x) * rs;
        v.y = (acc[i][1] + bi.y) * rs;
        v.z = (acc[i][2] + bi.z) * rs;
        v.w = (acc[i][3] + bi.w) * rs;
        if (R1){
            float4 r = *(const float4*)(R1 + idx);
            v.x += r.x; v.y += r.y; v.z += r.z; v.w += r.w;
        }
        if (R2){
            float4 r = *(const float4*)(R2 + idx);
            v.x += r.x; v.y += r.y; v.z += r.z; v.w += r.w;
        }
        *(float4*)(C + idx) = v;
    }
}

// ---------------- 3-phase chunked prefix sum over L, coalesced in d ------------
__global__ void scan1_kernel(const float* __restrict__ s, float* __restrict__ partial){
    int id = blockIdx.x;           // 64 blocks: b(2) x ch(16) x dblk(2)
    int b = id >> 5;
    int rem = id & 31;
    int ch = rem >> 1;
    int d = (rem & 1) * 256 + threadIdx.x;
    const float* base = s + ((size_t)b * LL + (size_t)ch * CH) * D + d;
    float sum = 0.f;
    for (int l = 0; l < CH; l++) sum += base[(size_t)l * D];
    partial[((size_t)b * D + d) * NCH + ch] = sum;
}

__global__ void scan2_kernel(float* __restrict__ partial){
    int t = blockIdx.x * 256 + threadIdx.x;   // 1024 = B*D channels
    float run = 0.f;
    float* p = partial + (size_t)t * NCH;
    for (int ch = 0; ch < NCH; ch++){ float v = p[ch]; p[ch] = run; run += v; }
}

__global__ void scan3_kernel(const float* __restrict__ s, const float* __restrict__ partial,
                             float* __restrict__ ret){
    int id = blockIdx.x;
    int b = id >> 5;
    int rem = id & 31;
    int ch = rem >> 1;
    int d = (rem & 1) * 256 + threadIdx.x;
    float run = partial[((size_t)b * D + d) * NCH + ch];
    const float invs = 0.022097086912079608f;  // 1/sqrt(2048)
    const float* base = s + ((size_t)b * LL + (size_t)ch * CH) * D + d;
    float* obase = ret + ((size_t)b * LL + (size_t)ch * CH) * D + d;
    for (int l = 0; l < CH; l++){
        run += base[(size_t)l * D];
        obase[(size_t)l * D] = run * invs;
    }
}

// ======================= split-bf16 head GEMM path =============================
// A' [MTOK][1024] bf16: [hi(512) | lo(512)]   (hi segment re-read for logical k<1024)
// B'T [VV][1024] bf16:  [hi(512) | lo(512)]   (stored transposed: row n, col k)
// logical K' = 1536:  seg0 Ahi*Bhi, seg1 Ahi*Blo, seg2 Alo*Bhi

__global__ void convA_kernel(const float* __restrict__ x, unsigned short* __restrict__ A2){
    int t = blockIdx.x, tid = threadIdx.x;   // 128 threads
    float4 v = ((const float4*)(x + (size_t)t * D))[tid];
    ushort4 h, l;
    h.x = f2bf(v.x); l.x = f2bf(v.x - bf2f(h.x));
    h.y = f2bf(v.y); l.y = f2bf(v.y - bf2f(h.y));
    h.z = f2bf(v.z); l.z = f2bf(v.z - bf2f(h.z));
    h.w = f2bf(v.w); l.w = f2bf(v.w - bf2f(h.w));
    size_t o = (size_t)t * 1024 + (size_t)tid * 4;
    *(ushort4*)(A2 + o)       = h;
    *(ushort4*)(A2 + o + 512) = l;
}

// transpose + split-convert head_W [512][32000] fp32 -> B'T [32000][1024] bf16
__global__ __launch_bounds__(256) void convB_kernel(const float* __restrict__ Bsrc,
                                                    unsigned short* __restrict__ Bt){
    __shared__ float tile[64][65];
    int n0 = blockIdx.x * 64;   // 500
    int k0 = blockIdx.y * 64;   // 8
    int tid = threadIdx.x;
    #pragma unroll
    for (int ph = 0; ph < 4; ph++){
        int idx = ph * 256 + tid;
        int r = idx >> 4;
        int c4 = idx & 15;
        float4 v = *(const float4*)(Bsrc + (size_t)(k0 + r) * VV + n0 + c4 * 4);
        tile[r][c4*4+0] = v.x; tile[r][c4*4+1] = v.y;
        tile[r][c4*4+2] = v.z; tile[r][c4*4+3] = v.w;
    }
    __syncthreads();
    int nn = tid >> 2;        // output row within tile (0..63)
    int kb = tid & 3;         // k quarter
    size_t orow = (size_t)(n0 + nn) * 1024;
    #pragma unroll
    for (int j4 = 0; j4 < 4; j4++){
        int kk = kb * 16 + j4 * 4;
        ushort4 h4, l4;
        float v0 = tile[kk + 0][nn], v1 = tile[kk + 1][nn];
        float v2 = tile[kk + 2][nn], v3 = tile[kk + 3][nn];
        h4.x = f2bf(v0); l4.x = f2bf(v0 - bf2f(h4.x));
        h4.y = f2bf(v1); l4.y = f2bf(v1 - bf2f(h4.y));
        h4.z = f2bf(v2); l4.z = f2bf(v2 - bf2f(h4.z));
        h4.w = f2bf(v3); l4.w = f2bf(v3 - bf2f(h4.w));
        size_t o = orow + (size_t)(k0 + kk);
        *(ushort4*)(Bt + o)       = h4;
        *(ushort4*)(Bt + o + 512) = l4;
    }
}

// m97-structure bf16 MFMA GEMM: C[4096][32000] = A'(:,K')  B'(K',:) + bias
// 128x128 tile, BK=32, 256 thr (4 waves, 2x2), 4x4 x mfma_f32_16x16x32_bf16/wave,
// double-buffered LDS staged via global_load_lds width 16.
__global__ __launch_bounds__(256) void head_mfma_kernel(
    const unsigned short* __restrict__ A2,   // [4096][1024]
    const unsigned short* __restrict__ Bt,   // [32000][1024]
    const float* __restrict__ bias,          // [32000]
    float* __restrict__ C)                   // [4096][32000]
{
    __shared__ unsigned short As[2][4096];   // [128 rows][32 k] bf16
    __shared__ unsigned short Bs[2][4096];   // [128 cols][32 k] bf16
    const int bm = blockIdx.x * 128;         // 32
    const int bn = blockIdx.y * 128;         // 250
    const int tid  = threadIdx.x;
    const int lane = tid & 63;
    const int wave = tid >> 6;
    const int wr = wave >> 1, wc = wave & 1;

    // staging: wave handles tile rows [wave*32, wave*32+32) as two 1KB chunks
    const int srow = wave * 32 + (lane >> 2);
    const int scol = (lane & 3) * 8;
    const unsigned short* Ag0 = A2 + (size_t)(bm + srow) * 1024 + scol;
    const unsigned short* Ag1 = Ag0 + (size_t)16 * 1024;
    const unsigned short* Bg0 = Bt + (size_t)(bn + srow) * 1024 + scol;
    const unsigned short* Bg1 = Bg0 + (size_t)16 * 1024;

    f32x4 acc[4][4] = {};

    const int frow = lane & 15;
    const int kq   = lane >> 4;
    const int abase = (wr * 64 + frow) * 32 + kq * 8;
    const int bbase = (wc * 64 + frow) * 32 + kq * 8;

    auto stagef = [&](int buf, int ko){
        // logical k' -> physical offsets: A [hi|hi|lo], B [hi|lo|hi]
        int ka = (ko < 512) ? ko : ko - 512;
        int kb = (ko >= 1024) ? ko - 1024 : ko;
        gload16(Ag0 + ka, &As[buf][wave * 1024]);
        gload16(Ag1 + ka, &As[buf][wave * 1024 + 512]);
        gload16(Bg0 + kb, &Bs[buf][wave * 1024]);
        gload16(Bg1 + kb, &Bs[buf][wave * 1024 + 512]);
    };

    stagef(0, 0);
    __syncthreads();

    for (int t = 0; t < 48; ++t){
        int cur = t & 1;
        if (t < 47) stagef(cur ^ 1, (t + 1) * 32);
        const unsigned short* Ab = &As[cur][0];
        const unsigned short* Bb = &Bs[cur][0];
        short8 af[4], bv[4];
        #pragma unroll
        for (int f = 0; f < 4; f++){
            af[f] = *(const short8*)(Ab + abase + f * 512);
            bv[f] = *(const short8*)(Bb + bbase + f * 512);
        }
        #pragma unroll
        for (int i = 0; i < 4; i++)
            #pragma unroll
            for (int j = 0; j < 4; j++)
                acc[i][j] = __builtin_amdgcn_mfma_f32_16x16x32_bf16(af[i], bv[j], acc[i][j], 0, 0, 0);
        __syncthreads();
    }

    // epilogue: C/D layout col = lane&15, row = (lane>>4)*4 + r  [m89-verified]
    #pragma unroll
    for (int j = 0; j < 4; j++){
        int col = bn + wc * 64 + j * 16 + frow;
        float bi = bias[col];
        #pragma unroll
        for (int i = 0; i < 4; i++){
            int row0 = bm + wr * 64 + i * 16 + kq * 4;
            #pragma unroll
            for (int r = 0; r < 4; r++)
                C[(size_t)(row0 + r) * VV + col] = acc[i][j][r] + bi;
        }
    }
}

extern "C" void kernel_launch(void* const* d_in, const int* in_sizes, int n_in,
                              void* d_out, int out_size, void* d_ws, size_t ws_size,
                              hipStream_t stream) {
    const int*   tokens        = (const int*)  d_in[0];
    const float* embed         = (const float*)d_in[1];
    const float* ln_scale      = (const float*)d_in[2];
    const float* ln_bias       = (const float*)d_in[3];
    const float* phase_W       = (const float*)d_in[4];
    const float* phase_b       = (const float*)d_in[5];
    const float* amp_W         = (const float*)d_in[6];
    const float* amp_b         = (const float*)d_in[7];
    const float* value_W       = (const float*)d_in[8];
    const float* value_b       = (const float*)d_in[9];
    const float* out_ln_scale  = (const float*)d_in[10];
    const float* out_ln_bias   = (const float*)d_in[11];
    const float* out_W         = (const float*)d_in[12];
    const float* out_b         = (const float*)d_in[13];
    const float* normout_scale = (const float*)d_in[14];
    const float* normout_bias  = (const float*)d_in[15];
    const float* head_W        = (const float*)d_in[16];
    const float* head_b        = (const float*)d_in[17];
    float* out = (float*)d_out;

    float* ws   = (float*)d_ws;
    float* h    = ws;                    // MTOK*D
    float* hn   = h    + (size_t)MTOK*D; // MTOK*D
    float* sbuf = hn   + (size_t)MTOK*D; // MTOK*D
    float* rbuf = sbuf + (size_t)MTOK*D; // MTOK*D
    float* cbuf = rbuf + (size_t)MTOK*D; // MTOK
    float* part = cbuf + MTOK;           // B*D*NCH

    // split-bf16 buffers (fast head path); fall back to fp32 GEMM if ws too small
    size_t used_f = (size_t)4*MTOK*D + MTOK + (size_t)BB*D*NCH;
    size_t abf_f  = (used_f + 255) & ~(size_t)255;
    size_t bbf_f  = abf_f + (size_t)MTOK * 1024 / 2;      // A': MTOK*1024 bf16
    size_t need   = (bbf_f + (size_t)VV * 1024 / 2) * sizeof(float);
    unsigned short* Abf = (unsigned short*)(ws + abf_f);
    unsigned short* Bbf = (unsigned short*)(ws + bbf_f);
    bool fast = (ws_size >= need);

    gather_kernel<<<MTOK, 128, 0, stream>>>(tokens, embed, h);

    for (int i = 0; i < NL; i++){
        ln_kernel<<<MTOK, 128, 0, stream>>>(h, ln_scale + i*D, ln_bias + i*D, hn);
        proj_kernel<<<MTOK/4, 256, 0, stream>>>(hn,
            phase_W + (size_t)i*D*P, phase_b + i*P,
            amp_W   + (size_t)i*D*P, amp_b   + i*P, cbuf);
        dim3 g1(D/64, MTOK/64);
        // sbuf = (hn @ vW + vb) * c
        gemm_kernel<<<g1, 256, 0, stream>>>(hn, value_W + (size_t)i*D*D, value_b + i*D,
                                            cbuf, nullptr, nullptr, sbuf, MTOK, D, D);
        scan1_kernel<<<64, 256, 0, stream>>>(sbuf, part);
        scan2_kernel<<<4, 256, 0, stream>>>(part);
        scan3_kernel<<<64, 256, 0, stream>>>(sbuf, part, rbuf);
        // rbuf = LN(rbuf) with out_ln params (in-place safe: per-thread read-before-write)
        ln_kernel<<<MTOK, 128, 0, stream>>>(rbuf, out_ln_scale + i*D, out_ln_bias + i*D, rbuf);
        // h = h + hn + (rbuf @ oW + ob)
        gemm_kernel<<<g1, 256, 0, stream>>>(rbuf, out_W + (size_t)i*D*D, out_b + i*D,
                                            nullptr, h, hn, h, MTOK, D, D);
    }

    ln_kernel<<<MTOK, 128, 0, stream>>>(h, normout_scale, normout_bias, hn);

    if (fast){
        convA_kernel<<<MTOK, 128, 0, stream>>>(hn, Abf);
        convB_kernel<<<dim3(VV/64, D/64), 256, 0, stream>>>(head_W, Bbf);
        head_mfma_kernel<<<dim3(MTOK/128, VV/128), 256, 0, stream>>>(Abf, Bbf, head_b, out);
    } else {
        dim3 gh(VV/64, MTOK/64);
        gemm_kernel<<<gh, 256, 0, stream>>>(hn, head_W, head_b,
                                            nullptr, nullptr, nullptr, out, MTOK, VV, D);
    }
}

// Round 4
// 1445.409 us; speedup vs baseline: 1.9747x; 1.1550x over previous
//
#include <hip/hip_runtime.h>
#include <math.h>

#define D 512
#define P 8
#define NL 4
#define BB 2
#define LL 2048
#define VV 32000
#define MTOK (BB*LL)   // 4096
#define CH 32
#define NCH (LL/CH)    // 64

__device__ __forceinline__ float softplusf(float x){
    if (x > 20.f) return x;
    return log1pf(expf(x));
}

// ---------------- fp16 helpers ----------------
__device__ __forceinline__ unsigned short f2h_u(float f){
    _Float16 h = (_Float16)f;
    union { _Float16 h; unsigned short u; } cv; cv.h = h; return cv.u;
}
__device__ __forceinline__ float h_lo_residual(float f, unsigned short hu){
    union { unsigned short u; _Float16 h; } cv; cv.u = hu;
    return f - (float)cv.h;
}

typedef __attribute__((ext_vector_type(8))) _Float16 f16x8;
typedef __attribute__((ext_vector_type(4))) float f32x4;

__device__ __forceinline__ void gload16(const void* g, void* l){
    // async global->LDS, 16B/lane; LDS dest = wave-uniform base + lane*16
    __builtin_amdgcn_global_load_lds(
        (const __attribute__((address_space(1))) void*)g,
        (__attribute__((address_space(3))) void*)l, 16, 0, 0);
}

// ---------------- embedding gather: h[t,:] = embed[tokens[t],:] ----------------
__global__ void gather_kernel(const int* __restrict__ tokens,
                              const float* __restrict__ embed,
                              float* __restrict__ h){
    int t = blockIdx.x;
    int tok = tokens[t];
    const float4* src = (const float4*)(embed + (size_t)tok * D);
    float4* dst = (float4*)(h + (size_t)t * D);
    dst[threadIdx.x] = src[threadIdx.x];
}

// ---------------- per-token LayerNorm (block = 128 threads, D=512) -------------
__global__ void ln_kernel(const float* __restrict__ x,
                          const float* __restrict__ g,
                          const float* __restrict__ b,
                          float* __restrict__ y){
    int t = blockIdx.x;
    int tid = threadIdx.x;
    const float4* xr = (const float4*)(x + (size_t)t * D);
    float4 v = xr[tid];
    float s = v.x + v.y + v.z + v.w;
    float q = v.x*v.x + v.y*v.y + v.z*v.z + v.w*v.w;
    #pragma unroll
    for (int off = 32; off; off >>= 1){
        s += __shfl_down(s, off);
        q += __shfl_down(q, off);
    }
    __shared__ float red[4];
    int wid = tid >> 6, lane = tid & 63;
    if (lane == 0){ red[wid] = s; red[2 + wid] = q; }
    __syncthreads();
    float mean = (red[0] + red[1]) * (1.f / D);
    float var  = (red[2] + red[3]) * (1.f / D) - mean * mean;
    float rstd = rsqrtf(var + 1e-5f);
    float4 gg = ((const float4*)g)[tid];
    float4 bb = ((const float4*)b)[tid];
    float4 o;
    o.x = (v.x - mean) * rstd * gg.x + bb.x;
    o.y = (v.y - mean) * rstd * gg.y + bb.y;
    o.z = (v.z - mean) * rstd * gg.z + bb.z;
    o.w = (v.w - mean) * rstd * gg.w + bb.w;
    ((float4*)(y + (size_t)t * D))[tid] = o;
}

// --------- phase/amp projections + per-token coefficient c (1 wave/token) ------
__global__ void proj_kernel(const float* __restrict__ hn,
                            const float* __restrict__ pW, const float* __restrict__ pb,
                            const float* __restrict__ aW, const float* __restrict__ ab,
                            float* __restrict__ cbuf){
    int wid = threadIdx.x >> 6;
    int lane = threadIdx.x & 63;
    int t = blockIdx.x * 4 + wid;
    const float* x = hn + (size_t)t * D;
    float ph[P] = {0.f,0.f,0.f,0.f,0.f,0.f,0.f,0.f};
    float am[P] = {0.f,0.f,0.f,0.f,0.f,0.f,0.f,0.f};
    int d0 = lane * 8;
    #pragma unroll
    for (int j = 0; j < 8; j++){
        float xv = x[d0 + j];
        const float* pr = pW + (size_t)(d0 + j) * P;
        const float* ar = aW + (size_t)(d0 + j) * P;
        #pragma unroll
        for (int p = 0; p < P; p++){ ph[p] += xv * pr[p]; am[p] += xv * ar[p]; }
    }
    #pragma unroll
    for (int off = 32; off; off >>= 1){
        #pragma unroll
        for (int p = 0; p < P; p++){
            ph[p] += __shfl_down(ph[p], off);
            am[p] += __shfl_down(am[p], off);
        }
    }
    if (lane == 0){
        float c = 0.f;
        #pragma unroll
        for (int p = 0; p < P; p++){
            float phase = tanhf(ph[p] + pb[p]) * 3.14159265358979323846f;
            float amp = softplusf(am[p] + ab[p]) + 0.1f;
            c += amp * (cosf(phase) + sinf(phase));
        }
        cbuf[t] = c;
    }
}

// ---------------- generic fp32 tiled GEMM (fallback path only) -----------------
__global__ __launch_bounds__(256) void gemm_kernel(
    const float* __restrict__ A, const float* __restrict__ B,
    const float* __restrict__ bias, const float* __restrict__ rowscale,
    const float* __restrict__ R1, const float* __restrict__ R2,
    float* __restrict__ C, int M, int N, int K)
{
    __shared__ float As[16][64];
    __shared__ float Bs[16][64];
    int bn = blockIdx.x * 64, bm = blockIdx.y * 64;
    int tid = threadIdx.x;
    int tx = tid & 15, ty = tid >> 4;
    float acc[4][4] = {};
    int arow = tid >> 2, acol = (tid & 3) * 4;
    int brow = tid >> 4, bcol = (tid & 15) * 4;
    for (int k0 = 0; k0 < K; k0 += 16){
        float4 av = *(const float4*)(A + (size_t)(bm + arow) * K + k0 + acol);
        As[acol + 0][arow] = av.x; As[acol + 1][arow] = av.y;
        As[acol + 2][arow] = av.z; As[acol + 3][arow] = av.w;
        float4 bv = *(const float4*)(B + (size_t)(k0 + brow) * N + bn + bcol);
        *(float4*)(&Bs[brow][bcol]) = bv;
        __syncthreads();
        #pragma unroll
        for (int k = 0; k < 16; k++){
            float ar[4], br[4];
            #pragma unroll
            for (int i = 0; i < 4; i++) ar[i] = As[k][ty * 4 + i];
            #pragma unroll
            for (int j = 0; j < 4; j++) br[j] = Bs[k][tx * 4 + j];
            #pragma unroll
            for (int i = 0; i < 4; i++)
                #pragma unroll
                for (int j = 0; j < 4; j++)
                    acc[i][j] += ar[i] * br[j];
        }
        __syncthreads();
    }
    float4 bi = *(const float4*)(bias + bn + tx * 4);
    #pragma unroll
    for (int i = 0; i < 4; i++){
        int m = bm + ty * 4 + i;
        float rs = rowscale ? rowscale[m] : 1.f;
        size_t idx = (size_t)m * N + bn + tx * 4;
        float4 v;
        v.x = (acc[i][0] + bi.x) * rs;
        v.y = (acc[i][1] + bi.y) * rs;
        v.z = (acc[i][2] + bi.z) * rs;
        v.w = (acc[i][3] + bi.w) * rs;
        if (R1){
            float4 r = *(const float4*)(R1 + idx);
            v.x += r.x; v.y += r.y; v.z += r.z; v.w += r.w;
        }
        if (R2){
            float4 r = *(const float4*)(R2 + idx);
            v.x += r.x; v.y += r.y; v.z += r.z; v.w += r.w;
        }
        *(float4*)(C + idx) = v;
    }
}

// ---------------- 3-phase chunked prefix sum over L, coalesced in d ------------
// 256 blocks: b(2) x ch(64) x dblk(2) -- full CU coverage
__global__ void scan1_kernel(const float* __restrict__ s, float* __restrict__ partial){
    int id = blockIdx.x;
    int b = id >> 7;
    int rem = id & 127;
    int ch = rem >> 1;
    int d = (rem & 1) * 256 + threadIdx.x;
    const float* base = s + ((size_t)b * LL + (size_t)ch * CH) * D + d;
    float sum = 0.f;
    for (int l = 0; l < CH; l++) sum += base[(size_t)l * D];
    partial[((size_t)b * D + d) * NCH + ch] = sum;
}

__global__ void scan2_kernel(float* __restrict__ partial){
    int t = blockIdx.x * 256 + threadIdx.x;   // 1024 = B*D channels
    float run = 0.f;
    float* p = partial + (size_t)t * NCH;
    for (int ch = 0; ch < NCH; ch++){ float v = p[ch]; p[ch] = run; run += v; }
}

__global__ void scan3_kernel(const float* __restrict__ s, const float* __restrict__ partial,
                             float* __restrict__ ret){
    int id = blockIdx.x;
    int b = id >> 7;
    int rem = id & 127;
    int ch = rem >> 1;
    int d = (rem & 1) * 256 + threadIdx.x;
    float run = partial[((size_t)b * D + d) * NCH + ch];
    const float invs = 0.022097086912079608f;  // 1/sqrt(2048)
    const float* base = s + ((size_t)b * LL + (size_t)ch * CH) * D + d;
    float* obase = ret + ((size_t)b * LL + (size_t)ch * CH) * D + d;
    for (int l = 0; l < CH; l++){
        run += base[(size_t)l * D];
        obase[(size_t)l * D] = run * invs;
    }
}

// ======================= fp16 2-term MFMA GEMM path ============================
// A' [M][1024] fp16: [hi(512) | lo(512)]  -> exact-A
// B  stored transposed [N][512] fp16 (rounded-B; A.Blo error ~2^-11 rel, safe)
// logical K' = 1024: seg0 Ahi.B, seg1 Alo.B  (B tile re-read: kb = ko & 511)

__global__ void convA_kernel(const float* __restrict__ x, unsigned short* __restrict__ A2){
    int t = blockIdx.x, tid = threadIdx.x;   // 128 threads
    float4 v = ((const float4*)(x + (size_t)t * D))[tid];
    ushort4 h, l;
    h.x = f2h_u(v.x); l.x = f2h_u(h_lo_residual(v.x, h.x));
    h.y = f2h_u(v.y); l.y = f2h_u(h_lo_residual(v.y, h.y));
    h.z = f2h_u(v.z); l.z = f2h_u(h_lo_residual(v.z, h.z));
    h.w = f2h_u(v.w); l.w = f2h_u(h_lo_residual(v.w, h.w));
    size_t o = (size_t)t * 1024 + (size_t)tid * 4;
    *(ushort4*)(A2 + o)       = h;
    *(ushort4*)(A2 + o + 512) = l;
}

// transpose+convert head_W [512][32000] fp32 -> Bt [32000][512] fp16
__global__ __launch_bounds__(256) void convB_kernel(const float* __restrict__ Bsrc,
                                                    unsigned short* __restrict__ Bt){
    __shared__ float tile[64][65];
    int n0 = blockIdx.x * 64;   // 500
    int k0 = blockIdx.y * 64;   // 8
    int tid = threadIdx.x;
    #pragma unroll
    for (int ph = 0; ph < 4; ph++){
        int idx = ph * 256 + tid;
        int r = idx >> 4;
        int c4 = idx & 15;
        float4 v = *(const float4*)(Bsrc + (size_t)(k0 + r) * VV + n0 + c4 * 4);
        tile[r][c4*4+0] = v.x; tile[r][c4*4+1] = v.y;
        tile[r][c4*4+2] = v.z; tile[r][c4*4+3] = v.w;
    }
    __syncthreads();
    int nn = tid >> 2;
    int kb = tid & 3;
    size_t orow = (size_t)(n0 + nn) * 512;
    #pragma unroll
    for (int j4 = 0; j4 < 4; j4++){
        int kk = kb * 16 + j4 * 4;
        ushort4 h4;
        h4.x = f2h_u(tile[kk + 0][nn]);
        h4.y = f2h_u(tile[kk + 1][nn]);
        h4.z = f2h_u(tile[kk + 2][nn]);
        h4.w = f2h_u(tile[kk + 3][nn]);
        *(ushort4*)(Bt + orow + (size_t)(k0 + kk)) = h4;
    }
}

// transpose+convert the 8 [512][512] layer weights -> Wt[m][n][k] fp16
__global__ __launch_bounds__(256) void convW_kernel(const float* __restrict__ vW,
                                                    const float* __restrict__ oW,
                                                    unsigned short* __restrict__ Wt){
    __shared__ float tile[64][65];
    int m = blockIdx.z;          // 0..7: value_W[0..3], out_W[0..3]
    const float* src = (m < NL) ? (vW + (size_t)m * D * D) : (oW + (size_t)(m - NL) * D * D);
    unsigned short* dst = Wt + (size_t)m * D * D;
    int n0 = blockIdx.x * 64;    // 8
    int k0 = blockIdx.y * 64;    // 8
    int tid = threadIdx.x;
    #pragma unroll
    for (int ph = 0; ph < 4; ph++){
        int idx = ph * 256 + tid;
        int r = idx >> 4;
        int c4 = idx & 15;
        float4 v = *(const float4*)(src + (size_t)(k0 + r) * D + n0 + c4 * 4);
        tile[r][c4*4+0] = v.x; tile[r][c4*4+1] = v.y;
        tile[r][c4*4+2] = v.z; tile[r][c4*4+3] = v.w;
    }
    __syncthreads();
    int nn = tid >> 2;
    int kb = tid & 3;
    size_t orow = (size_t)(n0 + nn) * 512;
    #pragma unroll
    for (int j4 = 0; j4 < 4; j4++){
        int kk = kb * 16 + j4 * 4;
        ushort4 h4;
        h4.x = f2h_u(tile[kk + 0][nn]);
        h4.y = f2h_u(tile[kk + 1][nn]);
        h4.z = f2h_u(tile[kk + 2][nn]);
        h4.w = f2h_u(tile[kk + 3][nn]);
        *(ushort4*)(dst + orow + (size_t)(k0 + kk)) = h4;
    }
}

// m97-structure fp16 MFMA GEMM: out[4096][32000] = A'[.,1024] Bt^T + bias
// 128x128 tile, BK=32, 256 thr (4 waves 2x2), 4x4 mfma_f32_16x16x32_f16/wave
__global__ __launch_bounds__(256) void head_mfma_kernel(
    const unsigned short* __restrict__ A2,   // [4096][1024] fp16
    const unsigned short* __restrict__ Bt,   // [32000][512] fp16
    const float* __restrict__ bias,          // [32000]
    float* __restrict__ C)                   // [4096][32000]
{
    __shared__ unsigned short As[2][4096];   // [128 rows][32 k]
    __shared__ unsigned short Bs[2][4096];   // [128 cols][32 k]
    const int bm = blockIdx.x * 128;         // 32
    const int bn = blockIdx.y * 128;         // 250
    const int tid  = threadIdx.x;
    const int lane = tid & 63;
    const int wave = tid >> 6;
    const int wr = wave >> 1, wc = wave & 1;

    const int srow = wave * 32 + (lane >> 2);
    const int scol = (lane & 3) * 8;
    const unsigned short* Ag0 = A2 + (size_t)(bm + srow) * 1024 + scol;
    const unsigned short* Ag1 = Ag0 + (size_t)16 * 1024;
    const unsigned short* Bg0 = Bt + (size_t)(bn + srow) * 512 + scol;
    const unsigned short* Bg1 = Bg0 + (size_t)16 * 512;

    f32x4 acc[4][4] = {};

    const int frow = lane & 15;
    const int kq   = lane >> 4;
    const int abase = (wr * 64 + frow) * 32 + kq * 8;
    const int bbase = (wc * 64 + frow) * 32 + kq * 8;

    auto stagef = [&](int buf, int ko){
        int kb = ko & 511;                    // B tile re-read for lo segment
        gload16(Ag0 + ko, &As[buf][wave * 1024]);
        gload16(Ag1 + ko, &As[buf][wave * 1024 + 512]);
        gload16(Bg0 + kb, &Bs[buf][wave * 1024]);
        gload16(Bg1 + kb, &Bs[buf][wave * 1024 + 512]);
    };

    stagef(0, 0);
    __syncthreads();

    for (int t = 0; t < 32; ++t){
        int cur = t & 1;
        if (t < 31) stagef(cur ^ 1, (t + 1) * 32);
        const unsigned short* Ab = &As[cur][0];
        const unsigned short* Bb = &Bs[cur][0];
        f16x8 af[4], bv[4];
        #pragma unroll
        for (int f = 0; f < 4; f++){
            af[f] = *(const f16x8*)(const void*)(Ab + abase + f * 512);
            bv[f] = *(const f16x8*)(const void*)(Bb + bbase + f * 512);
        }
        #pragma unroll
        for (int i = 0; i < 4; i++)
            #pragma unroll
            for (int j = 0; j < 4; j++)
                acc[i][j] = __builtin_amdgcn_mfma_f32_16x16x32_f16(af[i], bv[j], acc[i][j], 0, 0, 0);
        __syncthreads();
    }

    // C/D layout: col = lane&15, row = (lane>>4)*4 + r
    #pragma unroll
    for (int j = 0; j < 4; j++){
        int col = bn + wc * 64 + j * 16 + frow;
        float bi = bias[col];
        #pragma unroll
        for (int i = 0; i < 4; i++){
            int row0 = bm + wr * 64 + i * 16 + kq * 4;
            #pragma unroll
            for (int r = 0; r < 4; r++)
                C[(size_t)(row0 + r) * VV + col] = acc[i][j][r] + bi;
        }
    }
}

// fp16 2-term MFMA GEMM for the 512-wide layer GEMMs.
// C[M][512] = epi(A'[.,1024] Wt^T + bias); 128x64 tile, 256 blocks, 4 waves 2x2,
// wave tile 64x32 = 4x2 frags. Same staging/fragment geometry as head_mfma.
__global__ __launch_bounds__(256) void gemm16_kernel(
    const unsigned short* __restrict__ A2,   // [4096][1024] fp16
    const unsigned short* __restrict__ Bt,   // [512][512] fp16 (n-major)
    const float* __restrict__ bias,          // [512]
    const float* __restrict__ rowscale,      // [4096] or null
    const float* __restrict__ R1, const float* __restrict__ R2,
    float* __restrict__ C)                   // [4096][512]
{
    __shared__ unsigned short As[2][4096];   // 128 x 32
    __shared__ unsigned short Bs[2][2048];   // 64 x 32
    const int bm = blockIdx.x * 128;         // 32
    const int bn = blockIdx.y * 64;          // 8
    const int tid  = threadIdx.x;
    const int lane = tid & 63;
    const int wave = tid >> 6;
    const int wr = wave >> 1, wc = wave & 1;

    const int srow = wave * 32 + (lane >> 2);
    const int srb  = wave * 16 + (lane >> 2);
    const int scol = (lane & 3) * 8;
    const unsigned short* Ag0 = A2 + (size_t)(bm + srow) * 1024 + scol;
    const unsigned short* Ag1 = Ag0 + (size_t)16 * 1024;
    const unsigned short* Bg  = Bt + (size_t)(bn + srb) * 512 + scol;

    f32x4 acc[4][2] = {};

    const int frow = lane & 15;
    const int kq   = lane >> 4;
    const int abase = (wr * 64 + frow) * 32 + kq * 8;
    const int bbase = (wc * 32 + frow) * 32 + kq * 8;

    auto stagef = [&](int buf, int ko){
        int kb = ko & 511;
        gload16(Ag0 + ko, &As[buf][wave * 1024]);
        gload16(Ag1 + ko, &As[buf][wave * 1024 + 512]);
        gload16(Bg + kb,  &Bs[buf][wave * 512]);
    };

    stagef(0, 0);
    __syncthreads();

    for (int t = 0; t < 32; ++t){
        int cur = t & 1;
        if (t < 31) stagef(cur ^ 1, (t + 1) * 32);
        const unsigned short* Ab = &As[cur][0];
        const unsigned short* Bb = &Bs[cur][0];
        f16x8 af[4], bv[2];
        #pragma unroll
        for (int f = 0; f < 4; f++) af[f] = *(const f16x8*)(const void*)(Ab + abase + f * 512);
        #pragma unroll
        for (int f = 0; f < 2; f++) bv[f] = *(const f16x8*)(const void*)(Bb + bbase + f * 512);
        #pragma unroll
        for (int i = 0; i < 4; i++)
            #pragma unroll
            for (int j = 0; j < 2; j++)
                acc[i][j] = __builtin_amdgcn_mfma_f32_16x16x32_f16(af[i], bv[j], acc[i][j], 0, 0, 0);
        __syncthreads();
    }

    #pragma unroll
    for (int j = 0; j < 2; j++){
        int col = bn + wc * 32 + j * 16 + frow;
        float bi = bias[col];
        #pragma unroll
        for (int i = 0; i < 4; i++){
            int row0 = bm + wr * 64 + i * 16 + kq * 4;
            #pragma unroll
            for (int r = 0; r < 4; r++){
                int row = row0 + r;
                size_t idx = (size_t)row * D + col;
                float v = acc[i][j][r] + bi;
                if (rowscale) v *= rowscale[row];
                if (R1) v += R1[idx];
                if (R2) v += R2[idx];
                C[idx] = v;
            }
        }
    }
}

extern "C" void kernel_launch(void* const* d_in, const int* in_sizes, int n_in,
                              void* d_out, int out_size, void* d_ws, size_t ws_size,
                              hipStream_t stream) {
    const int*   tokens        = (const int*)  d_in[0];
    const float* embed         = (const float*)d_in[1];
    const float* ln_scale      = (const float*)d_in[2];
    const float* ln_bias       = (const float*)d_in[3];
    const float* phase_W       = (const float*)d_in[4];
    const float* phase_b       = (const float*)d_in[5];
    const float* amp_W         = (const float*)d_in[6];
    const float* amp_b         = (const float*)d_in[7];
    const float* value_W       = (const float*)d_in[8];
    const float* value_b       = (const float*)d_in[9];
    const float* out_ln_scale  = (const float*)d_in[10];
    const float* out_ln_bias   = (const float*)d_in[11];
    const float* out_W         = (const float*)d_in[12];
    const float* out_b         = (const float*)d_in[13];
    const float* normout_scale = (const float*)d_in[14];
    const float* normout_bias  = (const float*)d_in[15];
    const float* head_W        = (const float*)d_in[16];
    const float* head_b        = (const float*)d_in[17];
    float* out = (float*)d_out;

    float* ws   = (float*)d_ws;
    float* h    = ws;                    // MTOK*D
    float* hn   = h    + (size_t)MTOK*D; // MTOK*D
    float* sbuf = hn   + (size_t)MTOK*D; // MTOK*D
    float* rbuf = sbuf + (size_t)MTOK*D; // MTOK*D
    float* cbuf = rbuf + (size_t)MTOK*D; // MTOK
    float* part = cbuf + MTOK;           // B*D*NCH

    // fp16 buffers (fast path); fall back to fp32 GEMMs if ws too small
    size_t used_f = (size_t)4*MTOK*D + MTOK + (size_t)BB*D*NCH;
    size_t abf_f  = (used_f + 255) & ~(size_t)255;
    size_t bbf_f  = abf_f + (size_t)MTOK * 512;          // A': MTOK*1024 fp16
    size_t wt_f   = bbf_f + (size_t)VV * 256;            // Bt: VV*512 fp16
    size_t need   = (wt_f + (size_t)2*NL*D*D/2) * sizeof(float);  // Wt: 8*512*512 fp16
    unsigned short* Abf = (unsigned short*)(ws + abf_f);
    unsigned short* Bbf = (unsigned short*)(ws + bbf_f);
    unsigned short* Wt  = (unsigned short*)(ws + wt_f);
    bool fast = (ws_size >= need);

    gather_kernel<<<MTOK, 128, 0, stream>>>(tokens, embed, h);
    if (fast){
        convW_kernel<<<dim3(D/64, D/64, 2*NL), 256, 0, stream>>>(value_W, out_W, Wt);
        convB_kernel<<<dim3(VV/64, D/64), 256, 0, stream>>>(head_W, Bbf);
    }

    for (int i = 0; i < NL; i++){
        ln_kernel<<<MTOK, 128, 0, stream>>>(h, ln_scale + i*D, ln_bias + i*D, hn);
        proj_kernel<<<MTOK/4, 256, 0, stream>>>(hn,
            phase_W + (size_t)i*D*P, phase_b + i*P,
            amp_W   + (size_t)i*D*P, amp_b   + i*P, cbuf);
        if (fast){
            // sbuf = (hn @ vW + vb) * c
            convA_kernel<<<MTOK, 128, 0, stream>>>(hn, Abf);
            gemm16_kernel<<<dim3(MTOK/128, D/64), 256, 0, stream>>>(Abf,
                Wt + (size_t)i*D*D, value_b + i*D, cbuf, nullptr, nullptr, sbuf);
        } else {
            dim3 g1(D/64, MTOK/64);
            gemm_kernel<<<g1, 256, 0, stream>>>(hn, value_W + (size_t)i*D*D, value_b + i*D,
                                                cbuf, nullptr, nullptr, sbuf, MTOK, D, D);
        }
        scan1_kernel<<<256, 256, 0, stream>>>(sbuf, part);
        scan2_kernel<<<4, 256, 0, stream>>>(part);
        scan3_kernel<<<256, 256, 0, stream>>>(sbuf, part, rbuf);
        ln_kernel<<<MTOK, 128, 0, stream>>>(rbuf, out_ln_scale + i*D, out_ln_bias + i*D, rbuf);
        if (fast){
            // h = h + hn + (rbuf @ oW + ob)
            convA_kernel<<<MTOK, 128, 0, stream>>>(rbuf, Abf);
            gemm16_kernel<<<dim3(MTOK/128, D/64), 256, 0, stream>>>(Abf,
                Wt + (size_t)(NL + i)*D*D, out_b + i*D, nullptr, h, hn, h);
        } else {
            dim3 g1(D/64, MTOK/64);
            gemm_kernel<<<g1, 256, 0, stream>>>(rbuf, out_W + (size_t)i*D*D, out_b + i*D,
                                                nullptr, h, hn, h, MTOK, D, D);
        }
    }

    ln_kernel<<<MTOK, 128, 0, stream>>>(h, normout_scale, normout_bias, hn);

    if (fast){
        convA_kernel<<<MTOK, 128, 0, stream>>>(hn, Abf);
        head_mfma_kernel<<<dim3(MTOK/128, VV/128), 256, 0, stream>>>(Abf, Bbf, head_b, out);
    } else {
        dim3 gh(VV/64, MTOK/64);
        gemm_kernel<<<gh, 256, 0, stream>>>(hn, head_W, head_b,
                                            nullptr, nullptr, nullptr, out, MTOK, VV, D);
    }
}